// Round 3
// baseline (5312.006 us; speedup 1.0000x reference)
//
#include <hip/hip_runtime.h>
#include <math.h>

#define Bdim 32
#define Sdim 128
#define Tdim 50
#define Edim 768
#define Hdim 1024
#define Vdim 32000
#define EH   1792
#define INPD 1536
#define FCB  500    // fc blocks

typedef __bf16 bf16x8 __attribute__((ext_vector_type(8)));
typedef float  f32x4  __attribute__((ext_vector_type(4)));

__device__ __forceinline__ float sigmf(float v){ return 1.0f / (1.0f + expf(-v)); }

__device__ __forceinline__ ushort f2b(float v){
  unsigned int b = __float_as_uint(v);
  unsigned int r = (b + 0x7fffu + ((b >> 16) & 1u)) >> 16;
  return (ushort)r;
}
__device__ __forceinline__ float b2f(ushort u){
  return __uint_as_float(((unsigned int)u) << 16);
}

// ============ f32 -> bf16 convert ============
__global__ __launch_bounds__(256) void cvt_bf16(const float* __restrict__ src,
                                                ushort* __restrict__ dst, int n4){
  int i = blockIdx.x * 256 + threadIdx.x;
  if (i >= n4) return;
  float4 v = *(const float4*)(src + (size_t)i * 4);
  *(ushort4*)(dst + (size_t)i * 4) = make_ushort4(f2b(v.x), f2b(v.y), f2b(v.z), f2b(v.w));
}

__global__ __launch_bounds__(256) void cvt_w1h(const float* __restrict__ aW1,
                                               ushort* __restrict__ dst){
  int i = blockIdx.x * 256 + threadIdx.x;   // 262144 float4 groups
  if (i >= 262144) return;
  int k = (i & 255) * 4;
  int j = i >> 8;
  float4 v = *(const float4*)(aW1 + (size_t)j * EH + Edim + k);
  *(ushort4*)(dst + (size_t)j * 1024 + k) = make_ushort4(f2b(v.x), f2b(v.y), f2b(v.z), f2b(v.w));
}

__global__ __launch_bounds__(256) void zero_kernel(float* __restrict__ p, int n){
  int i = blockIdx.x * 256 + threadIdx.x;
  if (i < n) p[i] = 0.0f;
}

// ============ gather embeddings -> packed bf16 [k/8][b][8] (k<768) ============
__global__ __launch_bounds__(256) void gather_emb_p(const int* __restrict__ tseq,
                                                    const float* __restrict__ emb,
                                                    ushort* __restrict__ inpP){
  int g = blockIdx.x * 256 + threadIdx.x;   // T*B*96 groups of 8
  if (g >= Tdim * Bdim * 96) return;
  int kb = g % 96;
  int r = g / 96;
  int b = r % Bdim;
  int t = r / Bdim;
  int tok = tseq[b * Tdim + t];
  const float* src = emb + (size_t)tok * Edim + kb * 8;
  float4 a = *(const float4*)src;
  float4 c = *(const float4*)(src + 4);
  ushort* dst = inpP + (size_t)t * 49152 + kb * 256 + b * 8;
  *(ushort4*)(dst)     = make_ushort4(f2b(a.x), f2b(a.y), f2b(a.z), f2b(a.w));
  *(ushort4*)(dst + 4) = make_ushort4(f2b(c.x), f2b(c.y), f2b(c.z), f2b(c.w));
}

// ============ xW = x @ W1x^T -> bf16 (setup) ============
__global__ __launch_bounds__(256) void xw_gemm(const float* __restrict__ x,
                                               const float* __restrict__ w1,
                                               ushort* __restrict__ xWb){
  __shared__ float As[16][68];
  __shared__ float Ws[16][68];
  int tid = threadIdx.x;
  int m0 = blockIdx.x * 64;
  int n0 = blockIdx.y * 64;
  int lm = tid >> 2;
  int lk = (tid & 3) << 2;
  int tm = (tid >> 4) << 2;
  int tn = (tid & 15) << 2;
  float acc[4][4] = {};
  for (int k0 = 0; k0 < Edim; k0 += 16){
    float4 av = *(const float4*)&x [(size_t)(m0 + lm) * Edim + k0 + lk];
    float4 wv = *(const float4*)&w1[(size_t)(n0 + lm) * EH   + k0 + lk];
    As[lk+0][lm] = av.x; As[lk+1][lm] = av.y; As[lk+2][lm] = av.z; As[lk+3][lm] = av.w;
    Ws[lk+0][lm] = wv.x; Ws[lk+1][lm] = wv.y; Ws[lk+2][lm] = wv.z; Ws[lk+3][lm] = wv.w;
    __syncthreads();
#pragma unroll
    for (int k = 0; k < 16; k++){
      float a0 = As[k][tm+0], a1 = As[k][tm+1], a2 = As[k][tm+2], a3 = As[k][tm+3];
      float b0 = Ws[k][tn+0], b1 = Ws[k][tn+1], b2 = Ws[k][tn+2], b3 = Ws[k][tn+3];
      acc[0][0] += a0*b0; acc[0][1] += a0*b1; acc[0][2] += a0*b2; acc[0][3] += a0*b3;
      acc[1][0] += a1*b0; acc[1][1] += a1*b1; acc[1][2] += a1*b2; acc[1][3] += a1*b3;
      acc[2][0] += a2*b0; acc[2][1] += a2*b1; acc[2][2] += a2*b2; acc[2][3] += a2*b3;
      acc[3][0] += a3*b0; acc[3][1] += a3*b1; acc[3][2] += a3*b2; acc[3][3] += a3*b3;
    }
    __syncthreads();
  }
#pragma unroll
  for (int i = 0; i < 4; i++)
#pragma unroll
    for (int j = 0; j < 4; j++)
      xWb[(size_t)(m0 + tm + i) * Hdim + n0 + tn + j] = f2b(acc[i][j]);
}

// ============ MFMA tile: 16 rows x 32 b over K-range ============
// A row-major (lda elems). B packed [k/8][32][8]. D: row=(lane>>4)*4+reg, col=lane&15.
template<bool ABF16>
__device__ __forceinline__ void mfma_tile(const void* A, int lda, int rowBase,
                                          const ushort* __restrict__ Bp,
                                          int kbeg, int klen, int lane,
                                          f32x4& acc0, f32x4& acc1){
  int r = rowBase + (lane & 15);
  int q = lane >> 4;
  const ushort* Ab = (const ushort*)A;
  const float*  Af = (const float*)A;
#pragma unroll 4
  for (int kk = kbeg; kk < kbeg + klen; kk += 32){
    bf16x8 a;
    if (ABF16){
      a = *reinterpret_cast<const bf16x8*>(Ab + (size_t)r * lda + kk + q * 8);
    } else {
      const float* p = Af + (size_t)r * lda + kk + q * 8;
      float4 u = *(const float4*)p;
      float4 w = *(const float4*)(p + 4);
      union { ushort s[8]; bf16x8 v; } t;
      t.s[0]=f2b(u.x); t.s[1]=f2b(u.y); t.s[2]=f2b(u.z); t.s[3]=f2b(u.w);
      t.s[4]=f2b(w.x); t.s[5]=f2b(w.y); t.s[6]=f2b(w.z); t.s[7]=f2b(w.w);
      a = t.v;
    }
    const ushort* bbase = Bp + ((kk >> 3) + q) * 256 + (lane & 15) * 8;
    bf16x8 b0 = *reinterpret_cast<const bf16x8*>(bbase);
    bf16x8 b1 = *reinterpret_cast<const bf16x8*>(bbase + 128);
    acc0 = __builtin_amdgcn_mfma_f32_16x16x32_bf16(a, b0, acc0, 0, 0, 0);
    acc1 = __builtin_amdgcn_mfma_f32_16x16x32_bf16(a, b1, acc1, 0, 0, 0);
  }
}

// ============ fused LSTM layer: gates GEMM + cell update ============
// grid 64 blocks (j-groups of 16), 512 thr = 8 waves: gate = w&3, khalf = w>>2.
template<bool ABF16>
__global__ __launch_bounds__(512) void lstm_layer(const void* __restrict__ Wih, int Kin,
                                                  const void* __restrict__ Whh,
                                                  const ushort* __restrict__ inpP,
                                                  const ushort* __restrict__ hP,
                                                  const float* __restrict__ bih,
                                                  const float* __restrict__ bhh,
                                                  const float* __restrict__ cold,
                                                  float* __restrict__ cnew,
                                                  ushort* __restrict__ hPack){
  __shared__ float ld[8][32][18];
  int tid = threadIdx.x;
  int lane = tid & 63, w = tid >> 6;
  int gate = w & 3, khalf = w >> 2;
  int j0 = blockIdx.x * 16;
  int rowBase = gate * 1024 + j0;
  f32x4 acc0 = {0,0,0,0}, acc1 = {0,0,0,0};
  int kin_half = Kin >> 1;
  size_t wih_row = ABF16 ? (size_t)Kin : (size_t)Kin;
  mfma_tile<ABF16>(Wih, Kin, rowBase, inpP, khalf * kin_half, kin_half, lane, acc0, acc1);
  mfma_tile<ABF16>(Whh, Hdim, rowBase, hP, khalf * 512, 512, lane, acc0, acc1);
  (void)wih_row;
  int q = lane >> 4, c = lane & 15;
#pragma unroll
  for (int rr = 0; rr < 4; rr++){
    ld[w][c][q * 4 + rr]      = acc0[rr];
    ld[w][c + 16][q * 4 + rr] = acc1[rr];
  }
  __syncthreads();
  // epilogue: 512 threads = 32 b x 16 j
  int b = tid & 31, jl = tid >> 5;
  int j = j0 + jl;
  float gi = ld[0][b][jl] + ld[4][b][jl] + bih[j]        + bhh[j];
  float gf = ld[1][b][jl] + ld[5][b][jl] + bih[j + 1024] + bhh[j + 1024];
  float gg = ld[2][b][jl] + ld[6][b][jl] + bih[j + 2048] + bhh[j + 2048];
  float go = ld[3][b][jl] + ld[7][b][jl] + bih[j + 3072] + bhh[j + 3072];
  float cv = sigmf(gf) * cold[j * 32 + b] + sigmf(gi) * tanhf(gg);
  float hv = sigmf(go) * tanhf(cv);
  cnew[j * 32 + b] = cv;
  hPack[(j >> 3) * 256 + b * 8 + (j & 7)] = f2b(hv);
}

// ============ attn pre-activation: a = h2_old @ W1h^T, partials [kq][b][j] ============
__global__ __launch_bounds__(256) void attn_a_gemm(const ushort* __restrict__ W1h,
                                                   const ushort* __restrict__ h2P,
                                                   float* __restrict__ part){
  int lane = threadIdx.x & 63, w = threadIdx.x >> 6;
  int rowBase = blockIdx.x * 64 + w * 16;
  int kq = blockIdx.y;
  f32x4 acc0 = {0,0,0,0}, acc1 = {0,0,0,0};
  mfma_tile<true>(W1h, Hdim, rowBase, h2P, kq * 256, 256, lane, acc0, acc1);
  float* dst = part + (size_t)kq * 32768;
  int q = lane >> 4, c = lane & 15;
#pragma unroll
  for (int rr = 0; rr < 4; rr++){
    int row = rowBase + q * 4 + rr;
    dst[c * 1024 + row]        = acc0[rr];
    dst[(c + 16) * 1024 + row] = acc1[rr];
  }
}

// ============ scores[b][s]: lane owns 16 consecutive j, 16B bf16 loads ============
__global__ __launch_bounds__(256) void attn_score(const float* __restrict__ aPart,
                                                  const float* __restrict__ b1,
                                                  const float* __restrict__ w2,
                                                  const float* __restrict__ b2p,
                                                  const ushort* __restrict__ xWb,
                                                  float* __restrict__ scBuf){
  int b = blockIdx.x >> 2, sg = blockIdx.x & 3;
  int w = threadIdx.x >> 6, lane = threadIdx.x & 63;
  int jb = lane * 16;
  float ab[16], wv[16];
#pragma unroll
  for (int i = 0; i < 16; i++){
    int j = jb + i;
    float av = aPart[b * 1024 + j] + aPart[32768 + b * 1024 + j]
             + aPart[65536 + b * 1024 + j] + aPart[98304 + b * 1024 + j];
    ab[i] = av + b1[j];
    wv[i] = w2[j];
  }
  float b2v = b2p[0];
#pragma unroll
  for (int si = 0; si < 8; si++){
    int s = sg * 32 + w * 8 + si;
    const ushort* xrow = xWb + (size_t)(b * Sdim + s) * Hdim + jb;
    bf16x8 x0 = *reinterpret_cast<const bf16x8*>(xrow);
    bf16x8 x1 = *reinterpret_cast<const bf16x8*>(xrow + 8);
    float acc = 0.0f;
#pragma unroll
    for (int i = 0; i < 8; i++){
      float h0 = fmaxf((float)x0[i] + ab[i], 0.0f);
      float h1 = fmaxf((float)x1[i] + ab[i + 8], 0.0f);
      acc += h0 * wv[i] + h1 * wv[i + 8];
    }
    for (int off = 32; off; off >>= 1) acc += __shfl_xor(acc, off);
    if (lane == 0) scBuf[b * Sdim + s] = acc + b2v;
  }
}

// ============ softmax(scores) + context -> packed bf16 inp (k in [768,1536)) ============
__global__ __launch_bounds__(256) void attn_ctx2(const float* __restrict__ scBuf,
                                                 const ushort* __restrict__ xbf,
                                                 ushort* __restrict__ inpPt){
  __shared__ float sb[Sdim];
  int b = blockIdx.x / 3, ec = blockIdx.x % 3;
  int tid = threadIdx.x;
  if (tid < Sdim) sb[tid] = scBuf[b * Sdim + tid];
  __syncthreads();
  if (tid < 64){
    float v0 = sb[tid], v1 = sb[tid + 64];
    float m = fmaxf(v0, v1);
    for (int off = 32; off; off >>= 1) m = fmaxf(m, __shfl_xor(m, off));
    float e = expf(v0 - m) + expf(v1 - m);
    for (int off = 32; off; off >>= 1) e += __shfl_xor(e, off);
    float lse = m + logf(e);
    sb[tid]      = v0 - lse;
    sb[tid + 64] = v1 - lse;
  }
  __syncthreads();
  int e = ec * 256 + tid;
  const ushort* xb = xbf + (size_t)b * Sdim * Edim + e;
  float acc = 0.0f;
#pragma unroll 8
  for (int s = 0; s < Sdim; s++) acc += sb[s] * b2f(xb[(size_t)s * Edim]);
  int k = Edim + e;
  inpPt[(k >> 3) * 256 + b * 8 + (k & 7)] = f2b(acc);
}

// ============ fc: 512 thr, in-block K-split, fused softmax partials ============
template<bool ABF16>
__global__ __launch_bounds__(512) void fc_gemm(const void* __restrict__ fcW,
                                               const ushort* __restrict__ hP,
                                               const float* __restrict__ fcb,
                                               float* __restrict__ logits,
                                               float* __restrict__ partM,
                                               float* __restrict__ partS){
  __shared__ float ld[2][32][72];
  int tid = threadIdx.x;
  int lane = tid & 63, w = tid >> 6;
  int khalf = w >> 2;
  int v0 = blockIdx.x * 64 + (w & 3) * 16;
  f32x4 acc0 = {0,0,0,0}, acc1 = {0,0,0,0};
  mfma_tile<ABF16>(fcW, Hdim, v0, hP, khalf * 512, 512, lane, acc0, acc1);
  int q = lane >> 4, c = lane & 15;
#pragma unroll
  for (int rr = 0; rr < 4; rr++){
    int vloc = (w & 3) * 16 + q * 4 + rr;
    ld[khalf][c][vloc]      = acc0[rr];
    ld[khalf][c + 16][vloc] = acc1[rr];
  }
  __syncthreads();
  // combine halves + bias; thread: b = tid>>4, 4 v-values
  int b = tid >> 4, i0 = (tid & 15) * 4;
  int vg = blockIdx.x * 64 + i0;
  float o0 = ld[0][b][i0+0] + ld[1][b][i0+0] + fcb[vg+0];
  float o1 = ld[0][b][i0+1] + ld[1][b][i0+1] + fcb[vg+1];
  float o2 = ld[0][b][i0+2] + ld[1][b][i0+2] + fcb[vg+2];
  float o3 = ld[0][b][i0+3] + ld[1][b][i0+3] + fcb[vg+3];
  *(float4*)&logits[(size_t)b * Vdim + vg] = make_float4(o0, o1, o2, o3);
  // softmax partial over this block's 64 v for each b
  float m = fmaxf(fmaxf(o0, o1), fmaxf(o2, o3));
  float s = expf(o0 - m) + expf(o1 - m) + expf(o2 - m) + expf(o3 - m);
#pragma unroll
  for (int off = 1; off < 16; off <<= 1){
    float m2 = __shfl_xor(m, off);
    float s2 = __shfl_xor(s, off);
    float nm = fmaxf(m, m2);
    s = s * expf(m - nm) + s2 * expf(m2 - nm);
    m = nm;
  }
  if ((tid & 15) == 0){
    partM[b * FCB + blockIdx.x] = m;
    partS[b * FCB + blockIdx.x] = s;
  }
}

// ============ finalize lse[b] from 500 (m,s) pairs ============
__global__ __launch_bounds__(256) void lsm_finalize(const float* __restrict__ partM,
                                                    const float* __restrict__ partS,
                                                    float* __restrict__ lse){
  __shared__ float sm[256], ss[256];
  int b = blockIdx.x, tid = threadIdx.x;
  float m = -1e30f, s = 0.0f;
  for (int i = tid; i < FCB; i += 256){
    float m2 = partM[b * FCB + i];
    float s2 = partS[b * FCB + i];
    float nm = fmaxf(m, m2);
    s = s * expf(m - nm) + s2 * expf(m2 - nm);
    m = nm;
  }
  sm[tid] = m; ss[tid] = s;
  __syncthreads();
  for (int r = 128; r; r >>= 1){
    if (tid < r){
      float m2 = sm[tid + r], s2 = ss[tid + r];
      float nm = fmaxf(sm[tid], m2);
      ss[tid] = ss[tid] * expf(sm[tid] - nm) + s2 * expf(m2 - nm);
      sm[tid] = nm;
    }
    __syncthreads();
  }
  if (tid == 0) lse[b] = sm[0] + logf(ss[0]);
}

__global__ __launch_bounds__(256) void lsm_write(const float* __restrict__ logits,
                                                 const float* __restrict__ lse,
                                                 float* __restrict__ out, int t){
  int i = blockIdx.x * 256 + threadIdx.x;   // float4 idx
  if (i >= Bdim * Vdim / 4) return;
  int b = i / (Vdim / 4);
  float l = lse[b];
  float4 v = ((const float4*)logits)[i];
  float4* dst = (float4*)(out + ((size_t)b * Tdim + t) * Vdim);
  dst[i - b * (Vdim / 4)] = make_float4(v.x - l, v.y - l, v.z - l, v.w - l);
}

// =====================================================================
extern "C" void kernel_launch(void* const* d_in, const int* in_sizes, int n_in,
                              void* d_out, int out_size, void* d_ws, size_t ws_size,
                              hipStream_t stream){
  const float* x    = (const float*)d_in[0];
  const int*   tseq = (const int*)  d_in[1];
  const float* emb  = (const float*)d_in[2];
  const float* aW1  = (const float*)d_in[3];
  const float* ab1  = (const float*)d_in[4];
  const float* aW2  = (const float*)d_in[5];
  const float* ab2  = (const float*)d_in[6];
  const float* fcW  = (const float*)d_in[7];
  const float* fcb  = (const float*)d_in[8];
  const float* Wih[3] = {(const float*)d_in[9],  (const float*)d_in[13], (const float*)d_in[17]};
  const float* Whh[3] = {(const float*)d_in[10], (const float*)d_in[14], (const float*)d_in[18]};
  const float* bih[3] = {(const float*)d_in[11], (const float*)d_in[15], (const float*)d_in[19]};
  const float* bhh[3] = {(const float*)d_in[12], (const float*)d_in[16], (const float*)d_in[20]};
  float* out = (float*)d_out;

  // ---- workspace carve-up ----
  char* p = (char*)d_ws;
  ushort* xW_bf  = (ushort*)p;            p += (size_t)4096 * 1024 * 2;       // 8.39 MB
  ushort* W1h_bf = (ushort*)p;            p += (size_t)1024 * 1024 * 2;       // 2.10 MB
  ushort* inpP   = (ushort*)p;            p += (size_t)Tdim * 49152 * 2;      // 4.92 MB
  ushort* x_bf   = (ushort*)p;            p += (size_t)Bdim * Sdim * Edim * 2;// 6.29 MB
  float*  aPart  = (float*)p;             p += (size_t)4 * 32768 * 4;         // 0.52 MB
  float*  scBuf  = (float*)p;             p += (size_t)Bdim * Sdim * 4;
  float*  lseBuf = (float*)p;             p += 256;
  float*  partM  = (float*)p;             p += (size_t)Bdim * FCB * 4;
  float*  partS  = (float*)p;             p += (size_t)Bdim * FCB * 4;
  float*  logits = (float*)p;             p += (size_t)Bdim * Vdim * 4;       // 4.10 MB
  float*  cBuf   = (float*)p;             p += (size_t)6 * 32768 * 4;         // zeroed below
  ushort* hPackB = (ushort*)p;            p += (size_t)6 * 32768 * 2;         // contiguous after cBuf
  ushort* fcW_bf  = (ushort*)p;           p += (size_t)Vdim * Hdim * 2;       // 65.5 MB
  ushort* Wih_bf[3]; ushort* Whh_bf[3];
  Wih_bf[0] = (ushort*)p;                 p += (size_t)4096 * 1536 * 2;
  Whh_bf[0] = (ushort*)p;                 p += (size_t)4096 * 1024 * 2;
  Wih_bf[1] = (ushort*)p;                 p += (size_t)4096 * 1024 * 2;
  Whh_bf[1] = (ushort*)p;                 p += (size_t)4096 * 1024 * 2;
  Wih_bf[2] = (ushort*)p;                 p += (size_t)4096 * 1024 * 2;
  Whh_bf[2] = (ushort*)p;                 p += (size_t)4096 * 1024 * 2;
  size_t need_full = (size_t)(p - (char*)d_ws);
  bool full = ws_size >= need_full;

  // ---- setup ----
  zero_kernel<<<(294912 + 255) / 256, 256, 0, stream>>>(cBuf, 294912);  // cBuf + hPackB
  gather_emb_p<<<(Tdim * Bdim * 96 + 255) / 256, 256, 0, stream>>>(tseq, emb, inpP);
  cvt_w1h<<<262144 / 256, 256, 0, stream>>>(aW1, W1h_bf);
  cvt_bf16<<<(Bdim * Sdim * Edim / 4 + 255) / 256, 256, 0, stream>>>(x, x_bf, Bdim * Sdim * Edim / 4);
  xw_gemm<<<dim3(64, 16), 256, 0, stream>>>(x, aW1, xW_bf);
  if (full){
    cvt_bf16<<<(Vdim * Hdim / 4 + 255) / 256, 256, 0, stream>>>(fcW, fcW_bf, Vdim * Hdim / 4);
    cvt_bf16<<<(4096 * 1536 / 4 + 255) / 256, 256, 0, stream>>>(Wih[0], Wih_bf[0], 4096 * 1536 / 4);
    cvt_bf16<<<(4096 * 1024 / 4 + 255) / 256, 256, 0, stream>>>(Whh[0], Whh_bf[0], 4096 * 1024 / 4);
    cvt_bf16<<<(4096 * 1024 / 4 + 255) / 256, 256, 0, stream>>>(Wih[1], Wih_bf[1], 4096 * 1024 / 4);
    cvt_bf16<<<(4096 * 1024 / 4 + 255) / 256, 256, 0, stream>>>(Whh[1], Whh_bf[1], 4096 * 1024 / 4);
    cvt_bf16<<<(4096 * 1024 / 4 + 255) / 256, 256, 0, stream>>>(Wih[2], Wih_bf[2], 4096 * 1024 / 4);
    cvt_bf16<<<(4096 * 1024 / 4 + 255) / 256, 256, 0, stream>>>(Whh[2], Whh_bf[2], 4096 * 1024 / 4);
  }

  #define HP(l, par)  (hPackB + ((l) * 2 + (par)) * 32768)
  #define CB(l, par)  (cBuf   + ((l) * 2 + (par)) * 32768)

  for (int t = 0; t < Tdim; t++){
    int pn = t & 1, po = 1 - pn;
    ushort* inpPt = inpP + (size_t)t * 49152;

    attn_a_gemm<<<dim3(16, 4), 256, 0, stream>>>(W1h_bf, HP(2, po), aPart);
    attn_score<<<128, 256, 0, stream>>>(aPart, ab1, aW2, ab2, xW_bf, scBuf);
    attn_ctx2<<<96, 256, 0, stream>>>(scBuf, x_bf, inpPt);

    for (int l = 0; l < 3; l++){
      const ushort* bin = (l == 0) ? inpPt : HP(l - 1, pn);
      int kin = (l == 0) ? INPD : Hdim;
      if (full)
        lstm_layer<true ><<<64, 512, 0, stream>>>(Wih_bf[l], kin, Whh_bf[l], bin, HP(l, po),
                                                  bih[l], bhh[l], CB(l, po), CB(l, pn), HP(l, pn));
      else
        lstm_layer<false><<<64, 512, 0, stream>>>(Wih[l],    kin, Whh[l],    bin, HP(l, po),
                                                  bih[l], bhh[l], CB(l, po), CB(l, pn), HP(l, pn));
    }

    if (full) fc_gemm<true ><<<FCB, 512, 0, stream>>>(fcW_bf, HP(2, pn), fcb, logits, partM, partS);
    else      fc_gemm<false><<<FCB, 512, 0, stream>>>(fcW,    HP(2, pn), fcb, logits, partM, partS);
    lsm_finalize<<<Bdim, 256, 0, stream>>>(partM, partS, lseBuf);
    lsm_write<<<(Bdim * Vdim / 4 + 255) / 256, 256, 0, stream>>>(logits, lseBuf, out, t);
  }
}

// Round 4
// 4003.840 us; speedup vs baseline: 1.3267x; 1.3267x over previous
//
#include <hip/hip_runtime.h>
#include <math.h>

#define Bdim 32
#define Sdim 128
#define Tdim 50
#define Edim 768
#define Hdim 1024
#define Vdim 32000
#define EH   1792
#define INPD 1536
#define FCB  500    // fc blocks

typedef __bf16 bf16x8 __attribute__((ext_vector_type(8)));
typedef float  f32x4  __attribute__((ext_vector_type(4)));

__device__ __forceinline__ float sigmf(float v){ return 1.0f / (1.0f + expf(-v)); }

__device__ __forceinline__ ushort f2b(float v){
  unsigned int b = __float_as_uint(v);
  unsigned int r = (b + 0x7fffu + ((b >> 16) & 1u)) >> 16;
  return (ushort)r;
}
__device__ __forceinline__ float b2f(ushort u){
  return __uint_as_float(((unsigned int)u) << 16);
}

// ============ f32 -> bf16 convert ============
__global__ __launch_bounds__(256) void cvt_bf16(const float* __restrict__ src,
                                                ushort* __restrict__ dst, int n4){
  int i = blockIdx.x * 256 + threadIdx.x;
  if (i >= n4) return;
  float4 v = *(const float4*)(src + (size_t)i * 4);
  *(ushort4*)(dst + (size_t)i * 4) = make_ushort4(f2b(v.x), f2b(v.y), f2b(v.z), f2b(v.w));
}

__global__ __launch_bounds__(256) void cvt_w1h(const float* __restrict__ aW1,
                                               ushort* __restrict__ dst){
  int i = blockIdx.x * 256 + threadIdx.x;   // 262144 float4 groups
  if (i >= 262144) return;
  int k = (i & 255) * 4;
  int j = i >> 8;
  float4 v = *(const float4*)(aW1 + (size_t)j * EH + Edim + k);
  *(ushort4*)(dst + (size_t)j * 1024 + k) = make_ushort4(f2b(v.x), f2b(v.y), f2b(v.z), f2b(v.w));
}

__global__ __launch_bounds__(256) void zero_kernel(float* __restrict__ p, int n){
  int i = blockIdx.x * 256 + threadIdx.x;
  if (i < n) p[i] = 0.0f;
}

// ============ gather embeddings -> packed bf16 [k/8][b][8] (k<768) ============
__global__ __launch_bounds__(256) void gather_emb_p(const int* __restrict__ tseq,
                                                    const float* __restrict__ emb,
                                                    ushort* __restrict__ inpP){
  int g = blockIdx.x * 256 + threadIdx.x;   // T*B*96 groups of 8
  if (g >= Tdim * Bdim * 96) return;
  int kb = g % 96;
  int r = g / 96;
  int b = r % Bdim;
  int t = r / Bdim;
  int tok = tseq[b * Tdim + t];
  const float* src = emb + (size_t)tok * Edim + kb * 8;
  float4 a = *(const float4*)src;
  float4 c = *(const float4*)(src + 4);
  ushort* dst = inpP + (size_t)t * 49152 + kb * 256 + b * 8;
  *(ushort4*)(dst)     = make_ushort4(f2b(a.x), f2b(a.y), f2b(a.z), f2b(a.w));
  *(ushort4*)(dst + 4) = make_ushort4(f2b(c.x), f2b(c.y), f2b(c.z), f2b(c.w));
}

// ============ xW = x @ W1x^T -> bf16 (setup) ============
__global__ __launch_bounds__(256) void xw_gemm(const float* __restrict__ x,
                                               const float* __restrict__ w1,
                                               ushort* __restrict__ xWb){
  __shared__ float As[16][68];
  __shared__ float Ws[16][68];
  int tid = threadIdx.x;
  int m0 = blockIdx.x * 64;
  int n0 = blockIdx.y * 64;
  int lm = tid >> 2;
  int lk = (tid & 3) << 2;
  int tm = (tid >> 4) << 2;
  int tn = (tid & 15) << 2;
  float acc[4][4] = {};
  for (int k0 = 0; k0 < Edim; k0 += 16){
    float4 av = *(const float4*)&x [(size_t)(m0 + lm) * Edim + k0 + lk];
    float4 wv = *(const float4*)&w1[(size_t)(n0 + lm) * EH   + k0 + lk];
    As[lk+0][lm] = av.x; As[lk+1][lm] = av.y; As[lk+2][lm] = av.z; As[lk+3][lm] = av.w;
    Ws[lk+0][lm] = wv.x; Ws[lk+1][lm] = wv.y; Ws[lk+2][lm] = wv.z; Ws[lk+3][lm] = wv.w;
    __syncthreads();
#pragma unroll
    for (int k = 0; k < 16; k++){
      float a0 = As[k][tm+0], a1 = As[k][tm+1], a2 = As[k][tm+2], a3 = As[k][tm+3];
      float b0 = Ws[k][tn+0], b1 = Ws[k][tn+1], b2 = Ws[k][tn+2], b3 = Ws[k][tn+3];
      acc[0][0] += a0*b0; acc[0][1] += a0*b1; acc[0][2] += a0*b2; acc[0][3] += a0*b3;
      acc[1][0] += a1*b0; acc[1][1] += a1*b1; acc[1][2] += a1*b2; acc[1][3] += a1*b3;
      acc[2][0] += a2*b0; acc[2][1] += a2*b1; acc[2][2] += a2*b2; acc[2][3] += a2*b3;
      acc[3][0] += a3*b0; acc[3][1] += a3*b1; acc[3][2] += a3*b2; acc[3][3] += a3*b3;
    }
    __syncthreads();
  }
#pragma unroll
  for (int i = 0; i < 4; i++)
#pragma unroll
    for (int j = 0; j < 4; j++)
      xWb[(size_t)(m0 + tm + i) * Hdim + n0 + tn + j] = f2b(acc[i][j]);
}

// ============ MFMA tile: per-lane A-row r, 32 b cols, K-range ============
// A row-major (lda elems). B packed [k/8][32][8]. D: tile-row=(lane>>4)*4+reg, col=lane&15.
template<bool ABF16>
__device__ __forceinline__ void mfma_tile(const void* A, int lda, int r,
                                          const ushort* __restrict__ Bp,
                                          int kbeg, int klen, int lane,
                                          f32x4& acc0, f32x4& acc1){
  int q = lane >> 4;
  const ushort* Ab = (const ushort*)A;
  const float*  Af = (const float*)A;
#pragma unroll 4
  for (int kk = kbeg; kk < kbeg + klen; kk += 32){
    bf16x8 a;
    if (ABF16){
      a = *reinterpret_cast<const bf16x8*>(Ab + (size_t)r * lda + kk + q * 8);
    } else {
      const float* p = Af + (size_t)r * lda + kk + q * 8;
      float4 u = *(const float4*)p;
      float4 w = *(const float4*)(p + 4);
      union { ushort s[8]; bf16x8 v; } t;
      t.s[0]=f2b(u.x); t.s[1]=f2b(u.y); t.s[2]=f2b(u.z); t.s[3]=f2b(u.w);
      t.s[4]=f2b(w.x); t.s[5]=f2b(w.y); t.s[6]=f2b(w.z); t.s[7]=f2b(w.w);
      a = t.v;
    }
    const ushort* bbase = Bp + ((kk >> 3) + q) * 256 + (lane & 15) * 8;
    bf16x8 b0 = *reinterpret_cast<const bf16x8*>(bbase);
    bf16x8 b1 = *reinterpret_cast<const bf16x8*>(bbase + 128);
    acc0 = __builtin_amdgcn_mfma_f32_16x16x32_bf16(a, b0, acc0, 0, 0, 0);
    acc1 = __builtin_amdgcn_mfma_f32_16x16x32_bf16(a, b1, acc1, 0, 0, 0);
  }
}

// ============ fused LSTM layer, full-width: 256 blocks x 256 thr ============
// Block owns 4 units x 4 gates (mixed-gate 16-row tile); waves = 4 K-quarters.
// Tile-row tr: gate = tr>>2, unit = j0 + (tr&3). D: gate = lane>>4, unit = j0 + reg.
template<bool ABF16>
__global__ __launch_bounds__(256) void lstm_layer(const void* __restrict__ Wih, int Kin,
                                                  const void* __restrict__ Whh,
                                                  const ushort* __restrict__ inpP,
                                                  const ushort* __restrict__ hP,
                                                  const float* __restrict__ bih,
                                                  const float* __restrict__ bhh,
                                                  const float* __restrict__ cold,
                                                  float* __restrict__ cnew,
                                                  ushort* __restrict__ hPack){
  __shared__ float ld[4][4][4][32];   // [kq][gate][unit][b]
  int tid = threadIdx.x;
  int lane = tid & 63, kq = tid >> 6;
  int j0 = blockIdx.x * 4;
  int r = ((lane & 15) >> 2) * 1024 + j0 + (lane & 3);
  f32x4 acc0 = {0,0,0,0}, acc1 = {0,0,0,0};
  int kin_q = Kin >> 2;
  mfma_tile<ABF16>(Wih, Kin, r, inpP, kq * kin_q, kin_q, lane, acc0, acc1);
  mfma_tile<ABF16>(Whh, Hdim, r, hP, kq * 256, 256, lane, acc0, acc1);
  int g = lane >> 4, c = lane & 15;
#pragma unroll
  for (int rr = 0; rr < 4; rr++){
    ld[kq][g][rr][c]      = acc0[rr];
    ld[kq][g][rr][c + 16] = acc1[rr];
  }
  __syncthreads();
  if (tid < 128){
    int b = tid & 31, ul = tid >> 5;
    int j = j0 + ul;
    float gi = 0, gf = 0, gg = 0, go = 0;
#pragma unroll
    for (int k = 0; k < 4; k++){
      gi += ld[k][0][ul][b];
      gf += ld[k][1][ul][b];
      gg += ld[k][2][ul][b];
      go += ld[k][3][ul][b];
    }
    gi += bih[j]        + bhh[j];
    gf += bih[j + 1024] + bhh[j + 1024];
    gg += bih[j + 2048] + bhh[j + 2048];
    go += bih[j + 3072] + bhh[j + 3072];
    float cv = sigmf(gf) * cold[j * 32 + b] + sigmf(gi) * tanhf(gg);
    float hv = sigmf(go) * tanhf(cv);
    cnew[j * 32 + b] = cv;
    hPack[(j >> 3) * 256 + b * 8 + (j & 7)] = f2b(hv);
  }
}

// ============ attn pre-activation: aBuf[b][j] = (h2 @ W1h^T)[b][j] + b1[j] ============
// 64 blocks x 4 waves (kq in block, LDS combine)
__global__ __launch_bounds__(256) void attn_a_gemm(const ushort* __restrict__ W1h,
                                                   const ushort* __restrict__ h2P,
                                                   const float* __restrict__ b1,
                                                   float* __restrict__ aBuf){
  __shared__ float ld[4][32][17];
  int tid = threadIdx.x;
  int lane = tid & 63, kq = tid >> 6;
  int rowBase = blockIdx.x * 16;
  int r = rowBase + (lane & 15);
  f32x4 acc0 = {0,0,0,0}, acc1 = {0,0,0,0};
  mfma_tile<true>(W1h, Hdim, r, h2P, kq * 256, 256, lane, acc0, acc1);
  int q = lane >> 4, c = lane & 15;
#pragma unroll
  for (int rr = 0; rr < 4; rr++){
    ld[kq][c][q * 4 + rr]      = acc0[rr];
    ld[kq][c + 16][q * 4 + rr] = acc1[rr];
  }
  __syncthreads();
  int b = tid & 31, jl = tid >> 5;
#pragma unroll
  for (int h = 0; h < 2; h++){
    int j2 = jl + h * 8;
    float v = ld[0][b][j2] + ld[1][b][j2] + ld[2][b][j2] + ld[3][b][j2];
    int j = rowBase + j2;
    aBuf[b * 1024 + j] = v + b1[j];
  }
}

// ============ scores[b][s]: lane owns 16 consecutive j ============
__global__ __launch_bounds__(256) void attn_score(const float* __restrict__ aBuf,
                                                  const float* __restrict__ w2,
                                                  const float* __restrict__ b2p,
                                                  const ushort* __restrict__ xWb,
                                                  float* __restrict__ scBuf){
  int b = blockIdx.x >> 2, sg = blockIdx.x & 3;
  int w = threadIdx.x >> 6, lane = threadIdx.x & 63;
  int jb = lane * 16;
  float ab[16], wv[16];
#pragma unroll
  for (int i = 0; i < 4; i++){
    *(float4*)&ab[i * 4] = *(const float4*)&aBuf[b * 1024 + jb + i * 4];
    *(float4*)&wv[i * 4] = *(const float4*)&w2[jb + i * 4];
  }
  float b2v = b2p[0];
#pragma unroll
  for (int si = 0; si < 8; si++){
    int s = sg * 32 + w * 8 + si;
    const ushort* xrow = xWb + (size_t)(b * Sdim + s) * Hdim + jb;
    bf16x8 x0 = *reinterpret_cast<const bf16x8*>(xrow);
    bf16x8 x1 = *reinterpret_cast<const bf16x8*>(xrow + 8);
    float acc = 0.0f;
#pragma unroll
    for (int i = 0; i < 8; i++){
      float h0 = fmaxf((float)x0[i] + ab[i], 0.0f);
      float h1 = fmaxf((float)x1[i] + ab[i + 8], 0.0f);
      acc += h0 * wv[i] + h1 * wv[i + 8];
    }
    for (int off = 32; off; off >>= 1) acc += __shfl_xor(acc, off);
    if (lane == 0) scBuf[b * Sdim + s] = acc + b2v;
  }
}

// ============ softmax(scores) + context -> packed bf16 inp (k in [768,1536)) ============
__global__ __launch_bounds__(256) void attn_ctx2(const float* __restrict__ scBuf,
                                                 const ushort* __restrict__ xbf,
                                                 ushort* __restrict__ inpPt){
  __shared__ float sb[Sdim];
  int b = blockIdx.x / 3, ec = blockIdx.x % 3;
  int tid = threadIdx.x;
  if (tid < Sdim) sb[tid] = scBuf[b * Sdim + tid];
  __syncthreads();
  if (tid < 64){
    float v0 = sb[tid], v1 = sb[tid + 64];
    float m = fmaxf(v0, v1);
    for (int off = 32; off; off >>= 1) m = fmaxf(m, __shfl_xor(m, off));
    float e = expf(v0 - m) + expf(v1 - m);
    for (int off = 32; off; off >>= 1) e += __shfl_xor(e, off);
    float lse = m + logf(e);
    sb[tid]      = v0 - lse;
    sb[tid + 64] = v1 - lse;
  }
  __syncthreads();
  int e = ec * 256 + tid;
  const ushort* xb = xbf + (size_t)b * Sdim * Edim + e;
  float acc = 0.0f;
#pragma unroll 8
  for (int s = 0; s < Sdim; s++) acc += sb[s] * b2f(xb[(size_t)s * Edim]);
  int k = Edim + e;
  inpPt[(k >> 3) * 256 + b * 8 + (k & 7)] = f2b(acc);
}

// ============ fc: 512 thr, in-block K-split, fused softmax partials ============
template<bool ABF16>
__global__ __launch_bounds__(512) void fc_gemm(const void* __restrict__ fcW,
                                               const ushort* __restrict__ hP,
                                               const float* __restrict__ fcb,
                                               float* __restrict__ logits,
                                               float* __restrict__ partM,
                                               float* __restrict__ partS){
  __shared__ float ld[2][32][73];
  int tid = threadIdx.x;
  int lane = tid & 63, w = tid >> 6;
  int khalf = w >> 2;
  int v0 = blockIdx.x * 64 + (w & 3) * 16;
  int r = v0 + (lane & 15);
  f32x4 acc0 = {0,0,0,0}, acc1 = {0,0,0,0};
  mfma_tile<ABF16>(fcW, Hdim, r, hP, khalf * 512, 512, lane, acc0, acc1);
  int q = lane >> 4, c = lane & 15;
#pragma unroll
  for (int rr = 0; rr < 4; rr++){
    int vloc = (w & 3) * 16 + q * 4 + rr;
    ld[khalf][c][vloc]      = acc0[rr];
    ld[khalf][c + 16][vloc] = acc1[rr];
  }
  __syncthreads();
  int b = tid >> 4, i0 = (tid & 15) * 4;
  int vg = blockIdx.x * 64 + i0;
  float o0 = ld[0][b][i0+0] + ld[1][b][i0+0] + fcb[vg+0];
  float o1 = ld[0][b][i0+1] + ld[1][b][i0+1] + fcb[vg+1];
  float o2 = ld[0][b][i0+2] + ld[1][b][i0+2] + fcb[vg+2];
  float o3 = ld[0][b][i0+3] + ld[1][b][i0+3] + fcb[vg+3];
  *(float4*)&logits[(size_t)b * Vdim + vg] = make_float4(o0, o1, o2, o3);
  float m = fmaxf(fmaxf(o0, o1), fmaxf(o2, o3));
  float s = expf(o0 - m) + expf(o1 - m) + expf(o2 - m) + expf(o3 - m);
#pragma unroll
  for (int off = 1; off < 16; off <<= 1){
    float m2 = __shfl_xor(m, off);
    float s2 = __shfl_xor(s, off);
    float nm = fmaxf(m, m2);
    s = s * expf(m - nm) + s2 * expf(m2 - nm);
    m = nm;
  }
  if ((tid & 15) == 0){
    partM[b * FCB + blockIdx.x] = m;
    partS[b * FCB + blockIdx.x] = s;
  }
}

// ============ fused lse-finalize + write: grid (32 b, 32 chunks) ============
__global__ __launch_bounds__(256) void lsm_write(const float* __restrict__ logits,
                                                 const float* __restrict__ partM,
                                                 const float* __restrict__ partS,
                                                 float* __restrict__ out, int t){
  __shared__ float sm[256], ss[256];
  int b = blockIdx.x, chunk = blockIdx.y;
  int tid = threadIdx.x;
  float m = -1e30f, s = 0.0f;
  for (int i = tid; i < FCB; i += 256){
    float m2 = partM[b * FCB + i];
    float s2 = partS[b * FCB + i];
    float nm = fmaxf(m, m2);
    s = s * expf(m - nm) + s2 * expf(m2 - nm);
    m = nm;
  }
  sm[tid] = m; ss[tid] = s;
  __syncthreads();
  for (int r = 128; r; r >>= 1){
    if (tid < r){
      float m2 = sm[tid + r], s2 = ss[tid + r];
      float nm = fmaxf(sm[tid], m2);
      ss[tid] = ss[tid] * expf(sm[tid] - nm) + s2 * expf(m2 - nm);
      sm[tid] = nm;
    }
    __syncthreads();
  }
  float lse = sm[0] + logf(ss[0]);
  if (tid < 250){
    int i4 = chunk * 250 + tid;                       // float4 idx within b (8000 total)
    float4 v = ((const float4*)logits)[(size_t)b * 8000 + i4];
    float4* dst = (float4*)(out + ((size_t)b * Tdim + t) * Vdim);
    dst[i4] = make_float4(v.x - lse, v.y - lse, v.z - lse, v.w - lse);
  }
}

// =====================================================================
extern "C" void kernel_launch(void* const* d_in, const int* in_sizes, int n_in,
                              void* d_out, int out_size, void* d_ws, size_t ws_size,
                              hipStream_t stream){
  const float* x    = (const float*)d_in[0];
  const int*   tseq = (const int*)  d_in[1];
  const float* emb  = (const float*)d_in[2];
  const float* aW1  = (const float*)d_in[3];
  const float* ab1  = (const float*)d_in[4];
  const float* aW2  = (const float*)d_in[5];
  const float* ab2  = (const float*)d_in[6];
  const float* fcW  = (const float*)d_in[7];
  const float* fcb  = (const float*)d_in[8];
  const float* Wih[3] = {(const float*)d_in[9],  (const float*)d_in[13], (const float*)d_in[17]};
  const float* Whh[3] = {(const float*)d_in[10], (const float*)d_in[14], (const float*)d_in[18]};
  const float* bih[3] = {(const float*)d_in[11], (const float*)d_in[15], (const float*)d_in[19]};
  const float* bhh[3] = {(const float*)d_in[12], (const float*)d_in[16], (const float*)d_in[20]};
  float* out = (float*)d_out;

  // ---- workspace carve-up ----
  char* p = (char*)d_ws;
  ushort* xW_bf  = (ushort*)p;            p += (size_t)4096 * 1024 * 2;       // 8.39 MB
  ushort* W1h_bf = (ushort*)p;            p += (size_t)1024 * 1024 * 2;       // 2.10 MB
  ushort* inpP   = (ushort*)p;            p += (size_t)Tdim * 49152 * 2;      // 4.92 MB
  ushort* x_bf   = (ushort*)p;            p += (size_t)Bdim * Sdim * Edim * 2;// 6.29 MB
  float*  aBuf   = (float*)p;             p += (size_t)Bdim * Hdim * 4;       // 128 KB
  float*  scBuf  = (float*)p;             p += (size_t)Bdim * Sdim * 4;
  float*  partM  = (float*)p;             p += (size_t)Bdim * FCB * 4;
  float*  partS  = (float*)p;             p += (size_t)Bdim * FCB * 4;
  float*  logits = (float*)p;             p += (size_t)Bdim * Vdim * 4;       // 4.10 MB
  float*  cBuf   = (float*)p;             p += (size_t)6 * 32768 * 4;
  ushort* hPackB = (ushort*)p;            p += (size_t)6 * 32768 * 2;         // contiguous after cBuf
  ushort* fcW_bf  = (ushort*)p;           p += (size_t)Vdim * Hdim * 2;       // 65.5 MB
  ushort* Wih_bf[3]; ushort* Whh_bf[3];
  Wih_bf[0] = (ushort*)p;                 p += (size_t)4096 * 1536 * 2;
  Whh_bf[0] = (ushort*)p;                 p += (size_t)4096 * 1024 * 2;
  Wih_bf[1] = (ushort*)p;                 p += (size_t)4096 * 1024 * 2;
  Whh_bf[1] = (ushort*)p;                 p += (size_t)4096 * 1024 * 2;
  Wih_bf[2] = (ushort*)p;                 p += (size_t)4096 * 1024 * 2;
  Whh_bf[2] = (ushort*)p;                 p += (size_t)4096 * 1024 * 2;
  size_t need_full = (size_t)(p - (char*)d_ws);
  bool full = ws_size >= need_full;

  // ---- setup ----
  zero_kernel<<<(294912 + 255) / 256, 256, 0, stream>>>(cBuf, 294912);  // cBuf + hPackB
  gather_emb_p<<<(Tdim * Bdim * 96 + 255) / 256, 256, 0, stream>>>(tseq, emb, inpP);
  cvt_w1h<<<262144 / 256, 256, 0, stream>>>(aW1, W1h_bf);
  cvt_bf16<<<(Bdim * Sdim * Edim / 4 + 255) / 256, 256, 0, stream>>>(x, x_bf, Bdim * Sdim * Edim / 4);
  xw_gemm<<<dim3(64, 16), 256, 0, stream>>>(x, aW1, xW_bf);
  if (full){
    cvt_bf16<<<(Vdim * Hdim / 4 + 255) / 256, 256, 0, stream>>>(fcW, fcW_bf, Vdim * Hdim / 4);
    cvt_bf16<<<(4096 * 1536 / 4 + 255) / 256, 256, 0, stream>>>(Wih[0], Wih_bf[0], 4096 * 1536 / 4);
    cvt_bf16<<<(4096 * 1024 / 4 + 255) / 256, 256, 0, stream>>>(Whh[0], Whh_bf[0], 4096 * 1024 / 4);
    cvt_bf16<<<(4096 * 1024 / 4 + 255) / 256, 256, 0, stream>>>(Wih[1], Wih_bf[1], 4096 * 1024 / 4);
    cvt_bf16<<<(4096 * 1024 / 4 + 255) / 256, 256, 0, stream>>>(Whh[1], Whh_bf[1], 4096 * 1024 / 4);
    cvt_bf16<<<(4096 * 1024 / 4 + 255) / 256, 256, 0, stream>>>(Wih[2], Wih_bf[2], 4096 * 1024 / 4);
    cvt_bf16<<<(4096 * 1024 / 4 + 255) / 256, 256, 0, stream>>>(Whh[2], Whh_bf[2], 4096 * 1024 / 4);
  }

  #define HP(l, par)  (hPackB + ((l) * 2 + (par)) * 32768)
  #define CB(l, par)  (cBuf   + ((l) * 2 + (par)) * 32768)

  for (int t = 0; t < Tdim; t++){
    int pn = t & 1, po = 1 - pn;
    ushort* inpPt = inpP + (size_t)t * 49152;

    attn_a_gemm<<<64, 256, 0, stream>>>(W1h_bf, HP(2, po), ab1, aBuf);
    attn_score<<<128, 256, 0, stream>>>(aBuf, aW2, ab2, xW_bf, scBuf);
    attn_ctx2<<<96, 256, 0, stream>>>(scBuf, x_bf, inpPt);

    for (int l = 0; l < 3; l++){
      const ushort* bin = (l == 0) ? inpPt : HP(l - 1, pn);
      int kin = (l == 0) ? INPD : Hdim;
      if (full)
        lstm_layer<true ><<<256, 256, 0, stream>>>(Wih_bf[l], kin, Whh_bf[l], bin, HP(l, po),
                                                   bih[l], bhh[l], CB(l, po), CB(l, pn), HP(l, pn));
      else
        lstm_layer<false><<<256, 256, 0, stream>>>(Wih[l],    kin, Whh[l],    bin, HP(l, po),
                                                   bih[l], bhh[l], CB(l, po), CB(l, pn), HP(l, pn));
    }

    if (full) fc_gemm<true ><<<FCB, 512, 0, stream>>>(fcW_bf, HP(2, pn), fcb, logits, partM, partS);
    else      fc_gemm<false><<<FCB, 512, 0, stream>>>(fcW,    HP(2, pn), fcb, logits, partM, partS);
    lsm_write<<<dim3(Bdim, 32), 256, 0, stream>>>(logits, partM, partS, out, t);
  }
}